// Round 5
// baseline (479.782 us; speedup 1.0000x reference)
//
#include <hip/hip_runtime.h>
#include <hip/hip_bf16.h>
#include <math.h>

// Problem constants (fixed by reference)
#define B_TREES 64
#define N_NODES 65536
#define D 1024          // D_MEM == D_HID == 1024
#define D4 (D/4)        // 256 float4 per row
#define PIECE 16        // nodes per wave-piece
#define MAXP (N_NODES/PIECE + B_TREES)   // 4160 max pieces

__device__ __forceinline__ float dot4(const float4 a, const float4 b) {
    return a.x*b.x + a.y*b.y + a.z*b.z + a.w*b.w;
}
__device__ __forceinline__ void upd4(float4& a, const float sc,
                                     const float w0, const float4 x0,
                                     const float w1, const float4 x1,
                                     const float w2, const float4 x2,
                                     const float w3, const float4 x3) {
    a.x = a.x*sc + w0*x0.x + w1*x1.x + w2*x2.x + w3*x3.x;
    a.y = a.y*sc + w0*x0.y + w1*x1.y + w2*x2.y + w3*x3.y;
    a.z = a.z*sc + w0*x0.z + w1*x1.z + w2*x2.z + w3*x3.z;
    a.w = a.w*sc + w0*x0.w + w1*x1.w + w2*x2.w + w3*x3.w;
}

// ---------------- Kernel 1: v = ds@W (atomic-free) + setup on block(0,0) ----
// grid (4 m-tiles, 64 b), block 256. Each block computes v[b][m0:m0+256]
// with a full 1024-h loop; W slice is L2-served (4 MB total). Block (0,0)
// additionally does the lens scan + piece emission (was its own dispatch).
// lens dtype autodetect: JAX x64-off downcasts int64->int32.
__global__ __launch_bounds__(256) void combo_kernel(
        const float* __restrict__ ds, const float* __restrict__ W,
        const int* __restrict__ lens32,
        float* __restrict__ v, int* __restrict__ pbase,
        int* __restrict__ pseg, int* __restrict__ pstart,
        int* __restrict__ plen) {
    const int t = threadIdx.x;
    const int m = blockIdx.x * 256 + t;
    const int b = blockIdx.y;
    const float* dsrow = ds + (size_t)b * D;
    float acc = 0.f;
    #pragma unroll 8
    for (int h = 0; h < D; ++h)
        acc += dsrow[h] * W[(size_t)h * D + m];   // W coalesced; ds wave-uniform
    v[(size_t)b * D + m] = acc;

    if (blockIdx.x == 0 && blockIdx.y == 0) {
        __shared__ int sh_off[B_TREES + 1];
        __shared__ int sh_pb[B_TREES + 1];
        if (t < 64) {
            const int lane = t;
            int l32 = lens32[lane];
            int s = l32;
            #pragma unroll
            for (int o = 32; o > 0; o >>= 1) s += __shfl_xor(s, o, 64);
            const bool is32 = (s == N_NODES);
            int len = is32 ? l32 : (int)(((const long long*)lens32)[lane]);
            int scan = len;
            #pragma unroll
            for (int o = 1; o < 64; o <<= 1) {
                int u = __shfl_up(scan, o, 64);
                if (lane >= o) scan += u;
            }
            int pc = (len + PIECE - 1) / PIECE;
            int pscan = pc;
            #pragma unroll
            for (int o = 1; o < 64; o <<= 1) {
                int u = __shfl_up(pscan, o, 64);
                if (lane >= o) pscan += u;
            }
            sh_off[lane + 1] = scan;
            sh_pb[lane + 1]  = pscan;
            if (lane == 0) { sh_off[0] = 0; sh_pb[0] = 0; }
            pbase[lane + 1] = pscan;
            if (lane == 0) pbase[0] = 0;
        }
        __syncthreads();
        const int total = sh_pb[B_TREES];
        for (int p = t; p < total; p += 256) {
            int lo = 0, hi = B_TREES - 1;
            while (lo < hi) {
                int mid = (lo + hi + 1) >> 1;
                if (sh_pb[mid] <= p) lo = mid; else hi = mid - 1;
            }
            const int i  = p - sh_pb[lo];
            const int st = sh_off[lo] + i * PIECE;
            pseg[p]   = lo;
            pstart[p] = st;
            plen[p]   = min(PIECE, sh_off[lo + 1] - st);
        }
    }
}

// ---------------- Kernel 2: fused scores + online-softmax context partials ---
// One wave per piece (<=16 nodes, single segment). Lane l covers float4
// indices {l, 64+l, 128+l, 192+l}. Full pieces take a compile-time path in
// QUADS of rows: 16 loads in flight, 4 independent shuffle-reduce chains
// interleaved, ONE accumulator rescale per 4 rows. unroll 1 caps VGPRs.
__global__ __launch_bounds__(256) void fused_kernel(
        const float4* __restrict__ mb, const float4* __restrict__ v,
        const int* __restrict__ pseg, const int* __restrict__ pstart,
        const int* __restrict__ plen, const int* __restrict__ pbase,
        float* __restrict__ pm, float* __restrict__ pz, float4* __restrict__ pctx) {
    const int wave = threadIdx.x >> 6;
    const int lane = threadIdx.x & 63;
    const int p    = blockIdx.x * 4 + wave;
    if (p >= pbase[B_TREES]) return;

    const int seg = pseg[p];
    const int s0  = pstart[p];
    const int ln  = plen[p];

    const float4* vrow = v + (size_t)seg * D4;
    const float4 v0 = vrow[lane], v1 = vrow[64 + lane],
                 v2 = vrow[128 + lane], v3 = vrow[192 + lane];

    float4 a0 = make_float4(0.f,0.f,0.f,0.f), a1 = a0, a2 = a0, a3 = a0;
    float rm = -INFINITY, rz = 0.f;

    const float4* base = mb + (size_t)s0 * D4;

    if (ln == PIECE) {
        #pragma unroll 1
        for (int g = 0; g < PIECE; g += 4) {
            const float4* r0 = base + (size_t)g * D4;
            const float4* r1 = r0 + D4;
            const float4* r2 = r0 + 2 * D4;
            const float4* r3 = r0 + 3 * D4;
            const float4 x00=r0[lane], x01=r0[64+lane], x02=r0[128+lane], x03=r0[192+lane];
            const float4 x10=r1[lane], x11=r1[64+lane], x12=r1[128+lane], x13=r1[192+lane];
            const float4 x20=r2[lane], x21=r2[64+lane], x22=r2[128+lane], x23=r2[192+lane];
            const float4 x30=r3[lane], x31=r3[64+lane], x32=r3[128+lane], x33=r3[192+lane];
            float d0 = (dot4(x00,v0)+dot4(x01,v1)) + (dot4(x02,v2)+dot4(x03,v3));
            float d1 = (dot4(x10,v0)+dot4(x11,v1)) + (dot4(x12,v2)+dot4(x13,v3));
            float d2 = (dot4(x20,v0)+dot4(x21,v1)) + (dot4(x22,v2)+dot4(x23,v3));
            float d3 = (dot4(x30,v0)+dot4(x31,v1)) + (dot4(x32,v2)+dot4(x33,v3));
            #pragma unroll
            for (int o = 32; o > 0; o >>= 1) {   // 4 independent chains interleave
                d0 += __shfl_xor(d0, o, 64);
                d1 += __shfl_xor(d1, o, 64);
                d2 += __shfl_xor(d2, o, 64);
                d3 += __shfl_xor(d3, o, 64);
            }
            const float nm = fmaxf(rm, fmaxf(fmaxf(d0, d1), fmaxf(d2, d3)));
            const float sc = __expf(rm - nm);    // first iter: exp(-inf)=0
            const float w0 = __expf(d0 - nm), w1 = __expf(d1 - nm);
            const float w2 = __expf(d2 - nm), w3 = __expf(d3 - nm);
            upd4(a0, sc, w0, x00, w1, x10, w2, x20, w3, x30);
            upd4(a1, sc, w0, x01, w1, x11, w2, x21, w3, x31);
            upd4(a2, sc, w0, x02, w1, x12, w2, x22, w3, x32);
            upd4(a3, sc, w0, x03, w1, x13, w2, x23, w3, x33);
            rz = rz*sc + (w0 + w1) + (w2 + w3);
            rm = nm;
        }
    } else {
        for (int i = 0; i < ln; ++i) {
            const float4* mrow = base + (size_t)i * D4;
            const float4 m0 = mrow[lane],       m1 = mrow[64 + lane],
                         m2 = mrow[128 + lane], m3 = mrow[192 + lane];
            float d = (dot4(m0,v0)+dot4(m1,v1)) + (dot4(m2,v2)+dot4(m3,v3));
            #pragma unroll
            for (int o = 32; o > 0; o >>= 1) d += __shfl_xor(d, o, 64);
            const float nm = fmaxf(rm, d);
            const float sc = __expf(rm - nm);
            const float w  = __expf(d - nm);
            a0.x = a0.x*sc + w*m0.x; a0.y = a0.y*sc + w*m0.y;
            a0.z = a0.z*sc + w*m0.z; a0.w = a0.w*sc + w*m0.w;
            a1.x = a1.x*sc + w*m1.x; a1.y = a1.y*sc + w*m1.y;
            a1.z = a1.z*sc + w*m1.z; a1.w = a1.w*sc + w*m1.w;
            a2.x = a2.x*sc + w*m2.x; a2.y = a2.y*sc + w*m2.y;
            a2.z = a2.z*sc + w*m2.z; a2.w = a2.w*sc + w*m2.w;
            a3.x = a3.x*sc + w*m3.x; a3.y = a3.y*sc + w*m3.y;
            a3.z = a3.z*sc + w*m3.z; a3.w = a3.w*sc + w*m3.w;
            rz = rz*sc + w;
            rm = nm;
        }
    }

    if (lane == 0) { pm[p] = rm; pz[p] = rz; }
    float4* o = pctx + (size_t)p * D4;
    o[lane] = a0; o[64 + lane] = a1; o[128 + lane] = a2; o[192 + lane] = a3;
}

// ---------------- Kernel 3: finalize — merge piece partials per segment ------
// grid = 64 (one per segment), block = 256; thread t owns float4 index t.
__global__ void finalize_kernel(const int* __restrict__ pbase,
                                const float* __restrict__ pm, const float* __restrict__ pz,
                                const float4* __restrict__ pctx, float4* __restrict__ out) {
    const int b  = blockIdx.x;
    const int t  = threadIdx.x;
    const int q0 = pbase[b], q1 = pbase[b + 1];

    float mb_ = -INFINITY;
    for (int q = q0; q < q1; ++q) mb_ = fmaxf(mb_, pm[q]);
    float zb = 0.f;
    for (int q = q0; q < q1; ++q) zb += pz[q] * __expf(pm[q] - mb_);
    const float inv = 1.f / zb;

    float4 acc = make_float4(0.f,0.f,0.f,0.f);
    for (int q = q0; q < q1; ++q) {
        const float s = __expf(pm[q] - mb_);
        const float4 c = pctx[(size_t)q * D4 + t];
        acc.x += s * c.x; acc.y += s * c.y; acc.z += s * c.z; acc.w += s * c.w;
    }
    acc.x *= inv; acc.y *= inv; acc.z *= inv; acc.w *= inv;
    out[(size_t)b * D4 + t] = acc;
}

extern "C" void kernel_launch(void* const* d_in, const int* in_sizes, int n_in,
                              void* d_out, int out_size, void* d_ws, size_t ws_size,
                              hipStream_t stream) {
    const float* mb   = (const float*)d_in[0];       // [N, 1024]
    const float* ds   = (const float*)d_in[1];       // [64, 1024]
    const float* W    = (const float*)d_in[2];       // [1024, 1024]
    const int*   lens = (const int*)d_in[3];         // [64] int32 (autodetect int64)
    float*       out  = (float*)d_out;               // [64, 1024]

    // workspace layout (bytes, padded/aligned)
    char* ws = (char*)d_ws;
    int*   pbase  = (int*)(ws + 0);                  // 65 ints
    float* v      = (float*)(ws + 1024);             // 64*1024 floats = 256 KB
    int*   pseg   = (int*)(ws + 1024 + 262144);              // MAXP ints
    int*   pstart = (int*)(ws + 1024 + 262144 + 32768);      // MAXP ints
    int*   plen   = (int*)(ws + 1024 + 262144 + 65536);      // MAXP ints
    float* pm     = (float*)(ws + 1024 + 262144 + 98304);    // MAXP floats
    float* pz     = (float*)(ws + 1024 + 262144 + 131072);   // MAXP floats
    float4* pctx  = (float4*)(ws + 1024 + 262144 + 163840);  // MAXP*1024 floats ~= 17 MB

    {
        dim3 grid(4, 64);
        combo_kernel<<<grid, 256, 0, stream>>>(ds, W, lens, v,
                                               pbase, pseg, pstart, plen);
    }

    fused_kernel<<<(MAXP + 3) / 4, 256, 0, stream>>>(
        (const float4*)mb, (const float4*)v, pseg, pstart, plen, pbase,
        pm, pz, pctx);

    finalize_kernel<<<B_TREES, 256, 0, stream>>>(
        pbase, pm, pz, pctx, (float4*)out);
}

// Round 6
// 464.187 us; speedup vs baseline: 1.0336x; 1.0336x over previous
//
#include <hip/hip_runtime.h>
#include <hip/hip_bf16.h>
#include <math.h>

// Problem constants (fixed by reference)
#define B_TREES 64
#define N_NODES 65536
#define D 1024          // D_MEM == D_HID == 1024
#define D4 (D/4)        // 256 float4 per row
#define PIECE 8         // nodes per wave-piece (8 rows fit in VGPRs)
#define MAXP (N_NODES/PIECE + B_TREES)   // 8256 max pieces

__device__ __forceinline__ float dot4(const float4 a, const float4 b) {
    return a.x*b.x + a.y*b.y + a.z*b.z + a.w*b.w;
}

// ---------------- Kernel 1: parallel setup: scan + piece emission -----------
// lens dtype autodetect: JAX x64-off downcasts int64->int32.
__global__ void setup_kernel(const int* __restrict__ lens32,
                             int* __restrict__ pbase,
                             int* __restrict__ pseg, int* __restrict__ pstart,
                             int* __restrict__ plen) {
    __shared__ int sh_off[B_TREES + 1];
    __shared__ int sh_pb[B_TREES + 1];

    const int t = threadIdx.x;
    if (t < 64) {
        const int lane = t;
        int l32 = lens32[lane];
        int s = l32;
        #pragma unroll
        for (int o = 32; o > 0; o >>= 1) s += __shfl_xor(s, o, 64);
        const bool is32 = (s == N_NODES);
        int len = is32 ? l32 : (int)(((const long long*)lens32)[lane]);
        int scan = len;
        #pragma unroll
        for (int o = 1; o < 64; o <<= 1) {
            int u = __shfl_up(scan, o, 64);
            if (lane >= o) scan += u;
        }
        int pc = (len + PIECE - 1) / PIECE;
        int pscan = pc;
        #pragma unroll
        for (int o = 1; o < 64; o <<= 1) {
            int u = __shfl_up(pscan, o, 64);
            if (lane >= o) pscan += u;
        }
        sh_off[lane + 1] = scan;
        sh_pb[lane + 1]  = pscan;
        if (lane == 0) { sh_off[0] = 0; sh_pb[0] = 0; }
        pbase[lane + 1] = pscan;
        if (lane == 0) pbase[0] = 0;
    }
    __syncthreads();

    const int total = sh_pb[B_TREES];
    for (int p = t; p < total; p += 256) {
        int lo = 0, hi = B_TREES - 1;
        while (lo < hi) {
            int mid = (lo + hi + 1) >> 1;
            if (sh_pb[mid] <= p) lo = mid; else hi = mid - 1;
        }
        const int i  = p - sh_pb[lo];
        const int st = sh_off[lo] + i * PIECE;
        pseg[p]   = lo;
        pstart[p] = st;
        plen[p]   = min(PIECE, sh_off[lo + 1] - st);
    }
}

// ---------------- Kernel 2: v = ds @ W  (split-k, proven R2-R4 version) -----
// grid: (4 m-tiles of 256, 16 b-groups of 4, 8 h-chunks of 128); block 256
__global__ void v_kernel(const float* __restrict__ ds, const float* __restrict__ W,
                         float* __restrict__ v) {
    const int m  = blockIdx.x * 256 + threadIdx.x;
    const int b0 = blockIdx.y * 4;
    const int h0 = blockIdx.z * 128;
    float acc[4] = {0.f, 0.f, 0.f, 0.f};
    for (int h = h0; h < h0 + 128; ++h) {
        float wv = W[h * D + m];                 // coalesced
        #pragma unroll
        for (int j = 0; j < 4; ++j)
            acc[j] += ds[(b0 + j) * D + h] * wv; // wave-uniform -> scalar loads
    }
    #pragma unroll
    for (int j = 0; j < 4; ++j)
        atomicAdd(&v[(b0 + j) * D + m], acc[j]);
}

// ---------------- Kernel 3: fused scores + one-shot softmax context partials -
// One wave per piece (<=8 nodes, single segment). Lane l covers float4
// indices {l, 64+l, 128+l, 192+l}. Full pieces: ALL 32 loads issued up
// front (no dependent op in between), 8 independent dot/shuffle chains,
// ONE local softmax (no online rescale), register-resident accumulate.
__global__ __launch_bounds__(256, 2) void fused_kernel(
        const float4* __restrict__ mb, const float4* __restrict__ v,
        const int* __restrict__ pseg, const int* __restrict__ pstart,
        const int* __restrict__ plen, const int* __restrict__ pbase,
        float* __restrict__ pm, float* __restrict__ pz, float4* __restrict__ pctx) {
    const int wave = threadIdx.x >> 6;
    const int lane = threadIdx.x & 63;
    const int p    = blockIdx.x * 4 + wave;
    if (p >= pbase[B_TREES]) return;

    const int seg = pseg[p];
    const int s0  = pstart[p];
    const int ln  = plen[p];

    const float4* vrow = v + (size_t)seg * D4;
    const float4 v0 = vrow[lane], v1 = vrow[64 + lane],
                 v2 = vrow[128 + lane], v3 = vrow[192 + lane];

    float4 a0 = make_float4(0.f,0.f,0.f,0.f), a1 = a0, a2 = a0, a3 = a0;
    float rm, rz;

    const float4* base = mb + (size_t)s0 * D4;

    if (ln == PIECE) {
        // ---- phase 1: load all 8 rows (32 independent 16B loads) ----
        float4 x[PIECE][4];
        #pragma unroll
        for (int i = 0; i < PIECE; ++i) {
            const float4* r = base + (size_t)i * D4;
            x[i][0] = r[lane];        x[i][1] = r[64 + lane];
            x[i][2] = r[128 + lane];  x[i][3] = r[192 + lane];
        }
        // ---- phase 2: 8 independent dots ----
        float d[PIECE];
        #pragma unroll
        for (int i = 0; i < PIECE; ++i)
            d[i] = (dot4(x[i][0],v0) + dot4(x[i][1],v1))
                 + (dot4(x[i][2],v2) + dot4(x[i][3],v3));
        // ---- phase 3: batched butterfly reduce (8 chains interleaved) ----
        #pragma unroll
        for (int o = 32; o > 0; o >>= 1) {
            #pragma unroll
            for (int i = 0; i < PIECE; ++i) d[i] += __shfl_xor(d[i], o, 64);
        }
        // ---- phase 4: one-shot local softmax, no rescale ----
        float mloc = d[0];
        #pragma unroll
        for (int i = 1; i < PIECE; ++i) mloc = fmaxf(mloc, d[i]);
        float w[PIECE]; float z = 0.f;
        #pragma unroll
        for (int i = 0; i < PIECE; ++i) { w[i] = __expf(d[i] - mloc); z += w[i]; }
        // ---- phase 5: register-resident weighted accumulate ----
        #pragma unroll
        for (int i = 0; i < PIECE; ++i) {
            a0.x += w[i]*x[i][0].x; a0.y += w[i]*x[i][0].y;
            a0.z += w[i]*x[i][0].z; a0.w += w[i]*x[i][0].w;
            a1.x += w[i]*x[i][1].x; a1.y += w[i]*x[i][1].y;
            a1.z += w[i]*x[i][1].z; a1.w += w[i]*x[i][1].w;
            a2.x += w[i]*x[i][2].x; a2.y += w[i]*x[i][2].y;
            a2.z += w[i]*x[i][2].z; a2.w += w[i]*x[i][2].w;
            a3.x += w[i]*x[i][3].x; a3.y += w[i]*x[i][3].y;
            a3.z += w[i]*x[i][3].z; a3.w += w[i]*x[i][3].w;
        }
        rm = mloc; rz = z;
    } else {
        // ragged tail piece (<=64 of them): online-softmax scalar path
        rm = -INFINITY; rz = 0.f;
        for (int i = 0; i < ln; ++i) {
            const float4* mrow = base + (size_t)i * D4;
            const float4 m0 = mrow[lane],       m1 = mrow[64 + lane],
                         m2 = mrow[128 + lane], m3 = mrow[192 + lane];
            float d = (dot4(m0,v0)+dot4(m1,v1)) + (dot4(m2,v2)+dot4(m3,v3));
            #pragma unroll
            for (int o = 32; o > 0; o >>= 1) d += __shfl_xor(d, o, 64);
            const float nm = fmaxf(rm, d);
            const float sc = __expf(rm - nm);
            const float w  = __expf(d - nm);
            a0.x = a0.x*sc + w*m0.x; a0.y = a0.y*sc + w*m0.y;
            a0.z = a0.z*sc + w*m0.z; a0.w = a0.w*sc + w*m0.w;
            a1.x = a1.x*sc + w*m1.x; a1.y = a1.y*sc + w*m1.y;
            a1.z = a1.z*sc + w*m1.z; a1.w = a1.w*sc + w*m1.w;
            a2.x = a2.x*sc + w*m2.x; a2.y = a2.y*sc + w*m2.y;
            a2.z = a2.z*sc + w*m2.z; a2.w = a2.w*sc + w*m2.w;
            a3.x = a3.x*sc + w*m3.x; a3.y = a3.y*sc + w*m3.y;
            a3.z = a3.z*sc + w*m3.z; a3.w = a3.w*sc + w*m3.w;
            rz = rz*sc + w;
            rm = nm;
        }
    }

    if (lane == 0) { pm[p] = rm; pz[p] = rz; }
    float4* o = pctx + (size_t)p * D4;
    o[lane] = a0; o[64 + lane] = a1; o[128 + lane] = a2; o[192 + lane] = a3;
}

// ---------------- Kernel 4: finalize — merge piece partials per segment ------
// grid = 64 (one per segment), block = 256; thread t owns float4 index t.
__global__ void finalize_kernel(const int* __restrict__ pbase,
                                const float* __restrict__ pm, const float* __restrict__ pz,
                                const float4* __restrict__ pctx, float4* __restrict__ out) {
    const int b  = blockIdx.x;
    const int t  = threadIdx.x;
    const int q0 = pbase[b], q1 = pbase[b + 1];

    float mb_ = -INFINITY;
    for (int q = q0; q < q1; ++q) mb_ = fmaxf(mb_, pm[q]);
    float zb = 0.f;
    for (int q = q0; q < q1; ++q) zb += pz[q] * __expf(pm[q] - mb_);
    const float inv = 1.f / zb;

    float4 acc = make_float4(0.f,0.f,0.f,0.f);
    for (int q = q0; q < q1; ++q) {
        const float s = __expf(pm[q] - mb_);
        const float4 c = pctx[(size_t)q * D4 + t];
        acc.x += s * c.x; acc.y += s * c.y; acc.z += s * c.z; acc.w += s * c.w;
    }
    acc.x *= inv; acc.y *= inv; acc.z *= inv; acc.w *= inv;
    out[(size_t)b * D4 + t] = acc;
}

extern "C" void kernel_launch(void* const* d_in, const int* in_sizes, int n_in,
                              void* d_out, int out_size, void* d_ws, size_t ws_size,
                              hipStream_t stream) {
    const float* mb   = (const float*)d_in[0];       // [N, 1024]
    const float* ds   = (const float*)d_in[1];       // [64, 1024]
    const float* W    = (const float*)d_in[2];       // [1024, 1024]
    const int*   lens = (const int*)d_in[3];         // [64] int32 (autodetect int64)
    float*       out  = (float*)d_out;               // [64, 1024]

    // workspace layout (bytes, padded/aligned)
    char* ws = (char*)d_ws;
    int*   pbase  = (int*)(ws + 0);                  // 65 ints
    float* v      = (float*)(ws + 1024);             // 64*1024 floats = 256 KB
    int*   pseg   = (int*)(ws + 1024 + 262144);              // MAXP ints
    int*   pstart = (int*)(ws + 1024 + 262144 + 65536);      // MAXP ints
    int*   plen   = (int*)(ws + 1024 + 262144 + 131072);     // MAXP ints
    float* pm     = (float*)(ws + 1024 + 262144 + 196608);   // MAXP floats
    float* pz     = (float*)(ws + 1024 + 262144 + 262144);   // MAXP floats
    float4* pctx  = (float4*)(ws + 1048576);                 // MAXP*1024 floats ~= 34 MB

    hipMemsetAsync(v, 0, 64 * D * sizeof(float), stream);  // atomic target

    setup_kernel<<<1, 256, 0, stream>>>(lens, pbase, pseg, pstart, plen);

    {
        dim3 grid(4, 16, 8);
        v_kernel<<<grid, 256, 0, stream>>>(ds, W, v);
    }

    fused_kernel<<<(MAXP + 3) / 4, 256, 0, stream>>>(
        (const float4*)mb, (const float4*)v, pseg, pstart, plen, pbase,
        pm, pz, pctx);

    finalize_kernel<<<B_TREES, 256, 0, stream>>>(
        pbase, pm, pz, pctx, (float4*)out);
}